// Round 2
// baseline (291.767 us; speedup 1.0000x reference)
//
#include <hip/hip_runtime.h>

// DWT1D: x[32,64,16384] f32 -> out[32,192,8194] f32
// Planes: [0:64)=linear downsample, [64:128)=bior2.2 approx, [128:192)=detail.
//
// R2 (295.4 us): LDS-staged tile, 256 thr x 8 scalar outputs, scalar stores.
// R3/R4: pairwise outputs. Each thread computes 2 adjacent k per step from
// two aligned float4 LDS reads (windows overlap), stores float2 per plane
// (row base = 8 mod 16 floats? -> kL even-> base kL*4 B; kk even -> 8B
// aligned), non-temporal load/store hints on the touch-once streams.
// R4 fixes R3's compile error: nontemporal builtins need clang ext_vector
// types, not HIP_vector_type classes.

namespace {
constexpr int kN = 16384;   // input row length
constexpr int kL = 8194;    // output row length = (N + 6 - 1) / 2
constexpr int kTPB = 256;
constexpr int kPairsPerThread = 4;
constexpr int kPairsPerBlock = kTPB * kPairsPerThread;  // 1024 pairs
constexpr int kTile = 2 * kPairsPerBlock;               // 2048 outputs per block
constexpr int kStage = 2 * kTile + 8;                   // 4104 floats = 16416 B LDS

typedef float f32x4 __attribute__((ext_vector_type(4)));
typedef float f32x2 __attribute__((ext_vector_type(2)));

__device__ __forceinline__ int symi(int j) {
    j = (j < 0) ? (-j - 1) : j;
    j = (j >= kN) ? (2 * kN - 1 - j) : j;
    return j;
}

__global__ __launch_bounds__(kTPB) void dwt1d_kernel(const float* __restrict__ x,
                                                     float* __restrict__ out) {
    __shared__ float s[kStage];

    const int tile = blockIdx.x;
    const int row  = blockIdx.y;                // b*64 + c
    const int tid  = threadIdx.x;
    const int k0   = tile * kTile;
    const int s0   = 2 * k0 - 8;                // first staged global index (16B-aligned)
    const int lastk = min(kL - 1, k0 + kTile - 1);
    const int cnt  = 2 * lastk - s0 + 1;        // staged floats actually needed
    const int nchunk = (cnt + 3) >> 2;          // 4*nchunk <= kStage (=4104) always

    const float* __restrict__ xr = x + (size_t)row * kN;

    // ---- stage global -> LDS (mirror applied for out-of-range indices) ----
    for (int cck = tid; cck < nchunk; cck += kTPB) {
        const int g = s0 + 4 * cck;
        f32x4 v;
        if (g >= 0 && g + 3 < kN) {
            v = __builtin_nontemporal_load((const f32x4*)(xr + g));  // 16B aligned
        } else {
            v.x = xr[symi(g)];
            v.y = xr[symi(g + 1)];
            v.z = xr[symi(g + 2)];
            v.w = xr[symi(g + 3)];
        }
        *(f32x4*)(s + 4 * cck) = v;
    }
    __syncthreads();

    // bior2.2 decomposition filters (nonzero taps; symmetric)
    const float LO1 = -0.1767766952966369f;
    const float LO2 = 0.3535533905932738f;
    const float LO3 = 1.0606601717798212f;
    const float HI1 = 0.3535533905932738f;
    const float HI2 = -0.7071067811865476f;
    const float scale = 16384.0f / 8194.0f;

    const int b = row >> 6;
    const int c = row & 63;
    float* __restrict__ o0 = out + ((size_t)(b * 192 + c)) * kL;  // downsample plane
    float* __restrict__ o1 = o0 + (size_t)64 * kL;                // approx plane
    float* __restrict__ o2 = o0 + (size_t)128 * kL;               // detail plane

#pragma unroll
    for (int j = 0; j < kPairsPerThread; ++j) {
        const int p  = j * kTPB + tid;          // pair index within block
        const int kk = k0 + 2 * p;              // even; kk and kk+1 computed here
        if (kk >= kL) continue;                 // only the tiny tile-4 diverges

        // f0..f7 = x[sym(2kk-4 .. 2kk+3)] staged; m = LDS idx of x[2kk].
        // m = 4p + 8 -> m-4 is 16B aligned; m+3 <= kStage-1 (f7 loaded, unused).
        const int m = 4 * p + 8;
        const f32x4 qa = *(const f32x4*)(s + m - 4);  // f0 f1 f2 f3
        const f32x4 qb = *(const f32x4*)(s + m);      // f4 f5 f6 f7

        // k = kk:   v0..v4 = f0..f4 ; k = kk+1: v0..v4 = f2..f6
        const float a0 = LO3 * qa.z + LO2 * (qa.y + qa.w) + LO1 * (qa.x + qb.x);
        const float d0 = HI2 * qa.w + HI1 * (qa.z + qb.x);
        const float a1 = LO3 * qb.x + LO2 * (qa.w + qb.y) + LO1 * (qa.z + qb.z);
        const float d1 = HI2 * qb.y + HI1 * (qb.x + qb.z);

        // linear interp, align_corners=False; src>0 and i0+1<=kN-1 for all k
        // (max src = 16381.7), i0 - s0 >= 3 -> all reads inside the staged tile.
        float src0 = (kk + 0.5f) * scale - 0.5f;
        src0 = fminf(fmaxf(src0, 0.0f), (float)(kN - 1));
        const int i0 = (int)src0;
        const float w0 = src0 - (float)i0;
        const int a0i = i0 - s0;
        const float ds0 = s[a0i] * (1.0f - w0) + s[a0i + 1] * w0;

        float src1 = (kk + 1.5f) * scale - 0.5f;
        src1 = fminf(fmaxf(src1, 0.0f), (float)(kN - 1));
        const int i1 = (int)src1;
        const float w1 = src1 - (float)i1;
        const int a1i = i1 - s0;
        const float ds1 = s[a1i] * (1.0f - w1) + s[a1i + 1] * w1;

        // f32x2 stores: row base 8B-aligned (kL even), kk even -> 8B aligned.
        f32x2 vds; vds.x = ds0; vds.y = ds1;
        f32x2 va;  va.x  = a0;  va.y  = a1;
        f32x2 vd;  vd.x  = d0;  vd.y  = d1;
        __builtin_nontemporal_store(vds, (f32x2*)(o0 + kk));
        __builtin_nontemporal_store(va,  (f32x2*)(o1 + kk));
        __builtin_nontemporal_store(vd,  (f32x2*)(o2 + kk));
    }
}
}  // namespace

extern "C" void kernel_launch(void* const* d_in, const int* in_sizes, int n_in,
                              void* d_out, int out_size, void* d_ws, size_t ws_size,
                              hipStream_t stream) {
    const float* x = (const float*)d_in[0];
    float* out = (float*)d_out;
    dim3 grid((kL / 2 + kPairsPerBlock - 1) / kPairsPerBlock, 32 * 64);  // 5 x 2048
    dwt1d_kernel<<<grid, dim3(kTPB), 0, stream>>>(x, out);
}